// Round 1
// baseline (938.471 us; speedup 1.0000x reference)
//
#include <hip/hip_runtime.h>

// UniformShardedEmbeddingBags: B=1024, T=32, D=64, E=100000, L=50
// bag b in [0, B*T): t = b % T; out[b, :] = sum_{n in [off[b], off[b+1])} W[idx[n], t, :]
// One 64-lane wave per bag; lane = channel. Row load = 64 lanes x 4B = 256B coalesced.

constexpr int kT = 32;
constexpr int kD = 64;

__global__ __launch_bounds__(256) void embag_kernel(
    const float* __restrict__ weights,   // (E, T, D)
    const int*   __restrict__ features,  // (N,)
    const int*   __restrict__ offsets,   // (num_bags+1,)
    float*       __restrict__ out,       // (num_bags, D)
    int num_bags)
{
    const int gwave = (int)((blockIdx.x * 256u + threadIdx.x) >> 6);
    const int lane  = (int)(threadIdx.x & 63u);
    if (gwave >= num_bags) return;

    const int bag = gwave;
    const int t   = bag & (kT - 1);             // bag % T (T == 32)
    const float* wb = weights + (size_t)t * kD + lane;
    const size_t row_stride = (size_t)kT * kD;  // 2048 floats per embedding row group

    const int start = offsets[bag];
    const int end   = offsets[bag + 1];

    float a0 = 0.f, a1 = 0.f;
    int n = start;
    // main loop: 2 independent accumulators, unroll 4 -> ~8 loads in flight
    #pragma unroll 4
    for (; n + 2 <= end; n += 2) {
        const int e0 = features[n];
        const int e1 = features[n + 1];
        a0 += wb[(size_t)e0 * row_stride];
        a1 += wb[(size_t)e1 * row_stride];
    }
    if (n < end) {
        const int e0 = features[n];
        a0 += wb[(size_t)e0 * row_stride];
    }
    out[(size_t)bag * kD + lane] = a0 + a1;
}

extern "C" void kernel_launch(void* const* d_in, const int* in_sizes, int n_in,
                              void* d_out, int out_size, void* d_ws, size_t ws_size,
                              hipStream_t stream) {
    const float* weights  = (const float*)d_in[0];
    const int*   features = (const int*)d_in[1];
    const int*   offsets  = (const int*)d_in[2];
    float*       out      = (float*)d_out;

    const int num_bags = in_sizes[2] - 1;       // B*T
    const int threads  = 256;                   // 4 waves -> 4 bags per block
    const int waves    = num_bags;
    const int blocks   = (waves * 64 + threads - 1) / threads;

    embag_kernel<<<blocks, threads, 0, stream>>>(weights, features, offsets, out, num_bags);
}